// Round 10
// baseline (165.627 us; speedup 1.0000x reference)
//
#include <hip/hip_runtime.h>

#define EPSF 1e-8f

typedef __fp16   h2v   __attribute__((ext_vector_type(2)));
typedef _Float16 half8 __attribute__((ext_vector_type(8)));
typedef float    f32x16 __attribute__((ext_vector_type(16)));

constexpr int Bn = 64, Cc = 768, Nn = 1024, Mm = 100;

__device__ inline f32x16 zero16() {
    f32x16 z;
#pragma unroll
    for (int i = 0; i < 16; ++i) z[i] = 0.f;
    return z;
}

union U4H8 { uint4 u; half8 h; h2v p[4]; };

__device__ inline unsigned pkr(float a, float b) {
    union { h2v p; unsigned u; } cv;
    cv.p = __builtin_amdgcn_cvt_pkrtz(a, b);
    return cv.u;
}

// Fragment-major prep (unchanged layouts).
// GEMM1 A (normalized mem, hi/lo f16):  idx = ((cs*4 + mt)*64 + hb*32 + ml)*8 + j
// GEMM2 A (raw mem, transposed):        idx = ((ct*8 + ms)*64 + hm*32 + cl)*8 + jm
__global__ __launch_bounds__(256) void prep_kernel(const float* __restrict__ mem,
                                                   _Float16* __restrict__ mhiF,
                                                   _Float16* __restrict__ mloF,
                                                   _Float16* __restrict__ muF) {
    int m = blockIdx.x, t = threadIdx.x;
    float inv = 0.f;
    if (m < Mm) {
        float ss = 0.f;
        for (int c = t; c < Cc; c += 256) { float v = mem[m * Cc + c]; ss += v * v; }
        __shared__ float red[256];
        red[t] = ss; __syncthreads();
        for (int s = 128; s > 0; s >>= 1) { if (t < s) red[t] += red[t + s]; __syncthreads(); }
        inv = 1.f / fmaxf(sqrtf(red[0]), 1e-12f);
    }
    for (int c = t; c < Cc; c += 256) {
        float v = (m < Mm) ? mem[m * Cc + c] : 0.f;
        float nv = v * inv;
        _Float16 hh = (_Float16)nv;
        _Float16 ll = (_Float16)(nv - (float)hh);
        int cs = c >> 4, hb = (c >> 3) & 1, j = c & 7, mt = m >> 5, ml = m & 31;
        size_t idx = ((size_t)(cs * 4 + mt) * 64 + hb * 32 + ml) * 8 + j;
        mhiF[idx] = hh;
        mloF[idx] = ll;
        int ct = c >> 5, cl = c & 31, ms = m >> 4, hm = (m >> 3) & 1, jm = m & 7;
        size_t idx2 = ((size_t)(ct * 8 + ms) * 64 + hm * 32 + cl) * 8 + jm;
        muF[idx2] = (_Float16)v;
    }
}

// Kernel A (M-split x2): block = 4 waves = 2 px-groups x 2 m-halves.
// Each wave: full K (z loaded/converted per wave; partner hits L2/L3),
// 2 m-tiles (acc = 32 regs -> live set ~120 -> 4 waves/SIMD, 4096 waves
// ALL resident). Depth-4 nt z prefetch + depth-2 frag prefetch.
__global__ __launch_bounds__(256, 4) void score_kernel(
    const float* __restrict__ z, const _Float16* __restrict__ mhiF,
    const _Float16* __restrict__ mloF, float* __restrict__ attn_out) {
    __shared__ float r2x[3][2][2][32];  // [phase][pxgrp][mhalf][pl]

    const int tid = threadIdx.x;
    const int w = tid >> 6;
    const int mh = w & 1;          // m-half: tiles {0,1} or {2,3}
    const int pg = w >> 1;         // px-group within block
    const int l = tid & 63;
    const int gid = (blockIdx.x << 1) | pg;  // 0..2047
    const int b = gid >> 5;
    const int pxb = (gid & 31) * 32;
    const int pl = l & 31;
    const int h = l >> 5;
    const int t0 = mh * 2;
    const float* zr = z + (size_t)b * Cc * Nn + pxb + pl + (size_t)h * 8 * Nn;
    const uint4* mh4 = (const uint4*)mhiF;
    const uint4* ml4 = (const uint4*)mloF;

    f32x16 acc[2] = {zero16(), zero16()};
    float ss = 0.f;
    float zbuf[4][8];
    uint4 fh[2][2], fl[2][2];
#pragma unroll
    for (int d = 0; d < 4; ++d)
#pragma unroll
        for (int j = 0; j < 8; ++j)
            zbuf[d][j] = __builtin_nontemporal_load(&zr[(size_t)(d * 16 + j) * Nn]);
#pragma unroll
    for (int d = 0; d < 2; ++d)
#pragma unroll
        for (int t = 0; t < 2; ++t) {
            fh[d][t] = mh4[(d * 4 + t0 + t) * 64 + l];
            fl[d][t] = ml4[(d * 4 + t0 + t) * 64 + l];
        }

    for (int cso = 0; cso < 12; ++cso) {
#pragma unroll
        for (int i = 0; i < 4; ++i) {
            const int cs = cso * 4 + i;   // slot i, frag parity i&1 (compile-time)
            const int fb = i & 1;
            U4H8 zh, zl8;
#pragma unroll
            for (int t = 0; t < 4; ++t) {
                float u = zbuf[i][2 * t], v = zbuf[i][2 * t + 1];
                h2v p = __builtin_amdgcn_cvt_pkrtz(u, v);
                zh.p[t] = p;
                zl8.p[t] = __builtin_amdgcn_cvt_pkrtz(u - (float)p.x, v - (float)p.y);
                ss += u * u + v * v;
            }
            if (cs + 4 < 48) {  // z prefetch, 4 ahead, nontemporal
#pragma unroll
                for (int j = 0; j < 8; ++j)
                    zbuf[i][j] = __builtin_nontemporal_load(
                        &zr[(size_t)((cs + 4) * 16 + j) * Nn]);
            }
            U4H8 ah, al;
#pragma unroll
            for (int t = 0; t < 2; ++t) {
                ah.u = fh[fb][t]; al.u = fl[fb][t];
                acc[t] = __builtin_amdgcn_mfma_f32_32x32x16_f16(ah.h, zh.h, acc[t], 0, 0, 0);
                acc[t] = __builtin_amdgcn_mfma_f32_32x32x16_f16(al.h, zh.h, acc[t], 0, 0, 0);
                acc[t] = __builtin_amdgcn_mfma_f32_32x32x16_f16(ah.h, zl8.h, acc[t], 0, 0, 0);
            }
            if (cs + 2 < 48) {  // frag prefetch, 2 ahead (cacheable)
#pragma unroll
                for (int t = 0; t < 2; ++t) {
                    fh[fb][t] = mh4[((cs + 2) * 4 + t0 + t) * 64 + l];
                    fl[fb][t] = ml4[((cs + 2) * 4 + t0 + t) * 64 + l];
                }
            }
        }
    }

    // ---------------- softmax + hard shrinkage (wave owns m-half) ----------------
    ss += __shfl_xor(ss, 32);  // full-K ss computed in-wave (no exchange needed)
    float invn = 1.f / fmaxf(sqrtf(ss), 1e-12f);

    float a_[32];
#pragma unroll
    for (int r = 0; r < 32; ++r) {
        int lt = r >> 4, rr = r & 15;
        float v = acc[lt][rr] * invn;
        if (t0 + lt == 3 && !(h == 0 && rr < 4)) v = -3.0e38f;  // m >= 100 pad
        a_[r] = v;
    }
    float mx = -3.0e38f;
#pragma unroll
    for (int r = 0; r < 32; ++r) mx = fmaxf(mx, a_[r]);
    mx = fmaxf(mx, __shfl_xor(mx, 32));
    if (h == 0) r2x[0][pg][mh][pl] = mx;
    __syncthreads();
    mx = fmaxf(r2x[0][pg][0][pl], r2x[0][pg][1][pl]);

    float sum = 0.f;
#pragma unroll
    for (int r = 0; r < 32; ++r) { float e = expf(a_[r] - mx); a_[r] = e; sum += e; }
    sum += __shfl_xor(sum, 32);
    if (h == 0) r2x[1][pg][mh][pl] = sum;
    __syncthreads();
    float itot = 1.f / (r2x[1][pg][0][pl] + r2x[1][pg][1][pl]);

    float asum = 0.f;
#pragma unroll
    for (int r = 0; r < 32; ++r) {
        float wgt = a_[r] * itot;
        float d = wgt - 0.01f;
        float aa = (d > 0.f) ? (d * wgt) / (d + EPSF) : 0.f;
        a_[r] = aa; asum += aa;
    }
    asum += __shfl_xor(asum, 32);
    if (h == 0) r2x[2][pg][mh][pl] = asum;
    __syncthreads();
    float ia = 1.f / (r2x[2][pg][0][pl] + r2x[2][pg][1][pl] + EPSF);
#pragma unroll
    for (int r = 0; r < 32; ++r) a_[r] *= ia;

    // ---- store attn (own m-half) ----
    {
        size_t ob = (size_t)(gid * 32 + pl) * (size_t)Mm;
#pragma unroll
        for (int g = 0; g < 8; ++g) {
            int r0 = g * 4;
            int m0 = (t0 + (r0 >> 4)) * 32 + 8 * ((r0 >> 2) & 3) + 4 * h;
            if (m0 < Mm) {
                float4 v = make_float4(a_[r0], a_[r0 + 1], a_[r0 + 2], a_[r0 + 3]);
                *(float4*)&attn_out[ob + m0] = v;
            }
        }
    }
}

// Kernel B: z_hat = attn @ memory (unchanged from round 9).
__global__ __launch_bounds__(256, 4) void recon_kernel(
    const _Float16* __restrict__ muF, const float* __restrict__ attn_out,
    float* __restrict__ zhat) {
    const int tid = threadIdx.x;
    const int w = tid >> 6;
    const int l = tid & 63;
    const int gb = blockIdx.x;
    const int b = gb >> 5;
    const int pxb = (gb & 31) * 32;
    const int pl = l & 31;
    const int h = l >> 5;

    const float* ap = attn_out + (size_t)(gb * 32 + pl) * (size_t)Mm;
    uint4 bfr[8];
#pragma unroll
    for (int ms = 0; ms < 6; ++ms) {
        float4 fa = *(const float4*)&ap[ms * 16 + h * 8];
        float4 fb = *(const float4*)&ap[ms * 16 + h * 8 + 4];
        bfr[ms] = make_uint4(pkr(fa.x, fa.y), pkr(fa.z, fa.w),
                             pkr(fb.x, fb.y), pkr(fb.z, fb.w));
    }
    {
        float4 fa = (h == 0) ? *(const float4*)&ap[96] : make_float4(0.f, 0.f, 0.f, 0.f);
        bfr[6] = make_uint4(pkr(fa.x, fa.y), pkr(fa.z, fa.w), 0u, 0u);
        bfr[7] = make_uint4(0u, 0u, 0u, 0u);
    }

    const uint4* mu4 = (const uint4*)muF;
    float* zo = zhat + (size_t)b * Cc * Nn + pxb + pl;
    const int ct0 = w * 6;
#pragma unroll 1
    for (int cti = 0; cti < 6; cti += 2) {
        int ct = ct0 + cti;
        f32x16 a2 = zero16(), a3 = zero16();
#pragma unroll
        for (int ms = 0; ms < 7; ++ms) {  // ms=7 has B==0, skipped
            U4H8 A0, A1, Bf;
            A0.u = mu4[(ct * 8 + ms) * 64 + l];
            A1.u = mu4[((ct + 1) * 8 + ms) * 64 + l];
            Bf.u = bfr[ms];
            a2 = __builtin_amdgcn_mfma_f32_32x32x16_f16(A0.h, Bf.h, a2, 0, 0, 0);
            a3 = __builtin_amdgcn_mfma_f32_32x32x16_f16(A1.h, Bf.h, a3, 0, 0, 0);
        }
#pragma unroll
        for (int r = 0; r < 16; ++r) {
            int cl = (r & 3) + 8 * (r >> 2) + 4 * h;
            __builtin_nontemporal_store(a2[r], &zo[(size_t)(ct * 32 + cl) * Nn]);
            __builtin_nontemporal_store(a3[r], &zo[(size_t)(ct * 32 + 32 + cl) * Nn]);
        }
    }
}

extern "C" void kernel_launch(void* const* d_in, const int* in_sizes, int n_in,
                              void* d_out, int out_size, void* d_ws, size_t ws_size,
                              hipStream_t stream) {
    const float* z = (const float*)d_in[0];
    const float* mem = (const float*)d_in[1];
    float* out = (float*)d_out;
    float* zhat = out;                          // 64*768*1024
    float* attn = out + (size_t)Bn * Cc * Nn;   // 64*1024*100
    _Float16* mhiF = (_Float16*)d_ws;           // 192 KB
    _Float16* mloF = mhiF + 48 * 4 * 64 * 8;    // 192 KB
    _Float16* muF = mloF + 48 * 4 * 64 * 8;     // 192 KB

    prep_kernel<<<128, 256, 0, stream>>>(mem, mhiF, mloF, muF);
    score_kernel<<<1024, 256, 0, stream>>>(z, mhiF, mloF, attn);
    recon_kernel<<<2048, 256, 0, stream>>>(muF, attn, zhat);
}

// Round 11
// 117.110 us; speedup vs baseline: 1.4143x; 1.4143x over previous
//
#include <hip/hip_runtime.h>

#define EPSF 1e-8f

typedef __fp16   h2v   __attribute__((ext_vector_type(2)));
typedef _Float16 half8 __attribute__((ext_vector_type(8)));
typedef float    f32x16 __attribute__((ext_vector_type(16)));

constexpr int Bn = 64, Cc = 768, Nn = 1024, Mm = 100;

__device__ inline f32x16 zero16() {
    f32x16 z;
#pragma unroll
    for (int i = 0; i < 16; ++i) z[i] = 0.f;
    return z;
}

union U4H8 { uint4 u; half8 h; h2v p[4]; };

__device__ inline unsigned pkr(float a, float b) {
    union { h2v p; unsigned u; } cv;
    cv.p = __builtin_amdgcn_cvt_pkrtz(a, b);
    return cv.u;
}

// async global->LDS, 16 B per lane: LDS dest = (wave-uniform base) + lane*16,
// global src = per-lane pointer. Counted by vmcnt.
__device__ inline void gload_lds16(const void* g, void* s) {
    __builtin_amdgcn_global_load_lds(
        (const __attribute__((address_space(1))) unsigned int*)g,
        (__attribute__((address_space(3))) unsigned int*)s, 16, 0, 0);
}

// Fragment-major prep (unchanged layouts).
// GEMM1 A (normalized mem, hi/lo f16):  idx = ((cs*4 + mt)*64 + hb*32 + ml)*8 + j
// GEMM2 A (raw mem, transposed):        idx = ((ct*8 + ms)*64 + hm*32 + cl)*8 + jm
__global__ __launch_bounds__(256) void prep_kernel(const float* __restrict__ mem,
                                                   _Float16* __restrict__ mhiF,
                                                   _Float16* __restrict__ mloF,
                                                   _Float16* __restrict__ muF) {
    int m = blockIdx.x, t = threadIdx.x;
    float inv = 0.f;
    if (m < Mm) {
        float ss = 0.f;
        for (int c = t; c < Cc; c += 256) { float v = mem[m * Cc + c]; ss += v * v; }
        __shared__ float red[256];
        red[t] = ss; __syncthreads();
        for (int s = 128; s > 0; s >>= 1) { if (t < s) red[t] += red[t + s]; __syncthreads(); }
        inv = 1.f / fmaxf(sqrtf(red[0]), 1e-12f);
    }
    for (int c = t; c < Cc; c += 256) {
        float v = (m < Mm) ? mem[m * Cc + c] : 0.f;
        float nv = v * inv;
        _Float16 hh = (_Float16)nv;
        _Float16 ll = (_Float16)(nv - (float)hh);
        int cs = c >> 4, hb = (c >> 3) & 1, j = c & 7, mt = m >> 5, ml = m & 31;
        size_t idx = ((size_t)(cs * 4 + mt) * 64 + hb * 32 + ml) * 8 + j;
        mhiF[idx] = hh;
        mloF[idx] = ll;
        int ct = c >> 5, cl = c & 31, ms = m >> 4, hm = (m >> 3) & 1, jm = m & 7;
        size_t idx2 = ((size_t)(ct * 8 + ms) * 64 + hm * 32 + cl) * 8 + jm;
        muF[idx2] = (_Float16)v;
    }
}

// Kernel A: 4 waves/block, one 32-px group per wave (2048 waves). Mem
// fragments staged ONCE per block into LDS via async global_load_lds
// (double-buffered; frag L2 traffic /4, frag VGPRs freed -> ~4 waves/SIMD).
// Depth-4 nt z prefetch per wave. Softmax fully in-wave (round-9 numerics).
__global__ __launch_bounds__(256) void score_kernel(
    const float* __restrict__ z, const _Float16* __restrict__ mhiF,
    const _Float16* __restrict__ mloF, float* __restrict__ attn_out) {
    __shared__ uint4 fbuf[2][2][256];  // [buf][hi/lo][mt*64 + lane]  16 KB

    const int tid = threadIdx.x;
    const int w = tid >> 6;
    const int l = tid & 63;
    const int wid = (blockIdx.x << 2) | w;  // 0..2047
    const int b = wid >> 5;
    const int pxb = (wid & 31) * 32;
    const int pl = l & 31;
    const int h = l >> 5;
    const float* zr = z + (size_t)b * Cc * Nn + pxb + pl + (size_t)h * 8 * Nn;
    const uint4* mh4 = (const uint4*)mhiF;   // step s slice: mh4 + s*256
    const uint4* ml4 = (const uint4*)mloF;
    // wave w stages mt=w: 1 KB hi + 1 KB lo per K-step
    const uint4* gh = mh4 + w * 64 + l;
    const uint4* gl = ml4 + w * 64 + l;

    f32x16 acc[4] = {zero16(), zero16(), zero16(), zero16()};
    float ss = 0.f;
    float zbuf[4][8];
#pragma unroll
    for (int d = 0; d < 4; ++d)
#pragma unroll
        for (int j = 0; j < 8; ++j)
            zbuf[d][j] = __builtin_nontemporal_load(&zr[(size_t)(d * 16 + j) * Nn]);

    // prologue: stage step 0 into buf 0
    gload_lds16(gh, &fbuf[0][0][w * 64]);
    gload_lds16(gl, &fbuf[0][1][w * 64]);
    __syncthreads();

#pragma unroll 1
    for (int cso = 0; cso < 12; ++cso) {
#pragma unroll
        for (int i = 0; i < 4; ++i) {
            const int cs = cso * 4 + i;   // slot i, buffer parity i&1 (compile-time)
            const int cb = i & 1;
            if (cs + 1 < 48) {  // stage next step into other buffer (async)
                gload_lds16(gh + (cs + 1) * 256, &fbuf[cb ^ 1][0][w * 64]);
                gload_lds16(gl + (cs + 1) * 256, &fbuf[cb ^ 1][1][w * 64]);
            }
            U4H8 zh, zl8;
#pragma unroll
            for (int t = 0; t < 4; ++t) {
                float u = zbuf[i][2 * t], v = zbuf[i][2 * t + 1];
                h2v p = __builtin_amdgcn_cvt_pkrtz(u, v);
                zh.p[t] = p;
                zl8.p[t] = __builtin_amdgcn_cvt_pkrtz(u - (float)p.x, v - (float)p.y);
                ss += u * u + v * v;
            }
            if (cs + 4 < 48) {  // z prefetch, 4 ahead, nontemporal
#pragma unroll
                for (int j = 0; j < 8; ++j)
                    zbuf[i][j] = __builtin_nontemporal_load(
                        &zr[(size_t)((cs + 4) * 16 + j) * Nn]);
            }
            U4H8 ah, al;
#pragma unroll
            for (int mt = 0; mt < 4; ++mt) {
                ah.u = fbuf[cb][0][mt * 64 + l];
                al.u = fbuf[cb][1][mt * 64 + l];
                acc[mt] = __builtin_amdgcn_mfma_f32_32x32x16_f16(ah.h, zh.h, acc[mt], 0, 0, 0);
                acc[mt] = __builtin_amdgcn_mfma_f32_32x32x16_f16(al.h, zh.h, acc[mt], 0, 0, 0);
                acc[mt] = __builtin_amdgcn_mfma_f32_32x32x16_f16(ah.h, zl8.h, acc[mt], 0, 0, 0);
            }
            // drain staging (vmcnt) + all waves' ds reads done -> buffers safe
            __syncthreads();
        }
    }

    // ---------------- in-register softmax + hard shrinkage ----------------
    ss += __shfl_xor(ss, 32);
    float invn = 1.f / fmaxf(sqrtf(ss), 1e-12f);

    float a_[64];
#pragma unroll
    for (int r = 0; r < 64; ++r) {
        int mt = r >> 4, rr = r & 15;
        float v = acc[mt][rr] * invn;
        if (r >= 52) v = -3.0e38f;
        else if (r >= 48) v = (h == 0) ? v : -3.0e38f;  // tile3: only m=96..99 valid
        a_[r] = v;
    }
    float mx = -3.0e38f;
#pragma unroll
    for (int r = 0; r < 52; ++r) mx = fmaxf(mx, a_[r]);
    mx = fmaxf(mx, __shfl_xor(mx, 32));

    float sum = 0.f;
#pragma unroll
    for (int r = 0; r < 52; ++r) { float e = expf(a_[r] - mx); a_[r] = e; sum += e; }
    sum += __shfl_xor(sum, 32);
    float itot = 1.f / sum;

    float asum = 0.f;
#pragma unroll
    for (int r = 0; r < 52; ++r) {
        float w_ = a_[r] * itot;
        float d = w_ - 0.01f;
        float aa = (d > 0.f) ? (d * w_) / (d + EPSF) : 0.f;
        a_[r] = aa; asum += aa;
    }
    asum += __shfl_xor(asum, 32);
    float ia = 1.f / (asum + EPSF);
#pragma unroll
    for (int r = 0; r < 52; ++r) a_[r] *= ia;

    // ---- store attn (normal stores: re-read by recon) ----
    {
        size_t ob = (size_t)(wid * 32 + pl) * (size_t)Mm;
#pragma unroll
        for (int g = 0; g < 13; ++g) {
            int r0 = g * 4;
            int m0 = (r0 >> 4) * 32 + 8 * ((r0 >> 2) & 3) + 4 * h;
            if (g < 12 || h == 0) {
                float4 v = make_float4(a_[r0], a_[r0 + 1], a_[r0 + 2], a_[r0 + 3]);
                *(float4*)&attn_out[ob + m0] = v;
            }
        }
    }
}

// Kernel B: z_hat = attn @ memory (unchanged from round 9).
__global__ __launch_bounds__(256, 4) void recon_kernel(
    const _Float16* __restrict__ muF, const float* __restrict__ attn_out,
    float* __restrict__ zhat) {
    const int tid = threadIdx.x;
    const int w = tid >> 6;
    const int l = tid & 63;
    const int gb = blockIdx.x;
    const int b = gb >> 5;
    const int pxb = (gb & 31) * 32;
    const int pl = l & 31;
    const int h = l >> 5;

    const float* ap = attn_out + (size_t)(gb * 32 + pl) * (size_t)Mm;
    uint4 bfr[8];
#pragma unroll
    for (int ms = 0; ms < 6; ++ms) {
        float4 fa = *(const float4*)&ap[ms * 16 + h * 8];
        float4 fb = *(const float4*)&ap[ms * 16 + h * 8 + 4];
        bfr[ms] = make_uint4(pkr(fa.x, fa.y), pkr(fa.z, fa.w),
                             pkr(fb.x, fb.y), pkr(fb.z, fb.w));
    }
    {
        float4 fa = (h == 0) ? *(const float4*)&ap[96] : make_float4(0.f, 0.f, 0.f, 0.f);
        bfr[6] = make_uint4(pkr(fa.x, fa.y), pkr(fa.z, fa.w), 0u, 0u);
        bfr[7] = make_uint4(0u, 0u, 0u, 0u);
    }

    const uint4* mu4 = (const uint4*)muF;
    float* zo = zhat + (size_t)b * Cc * Nn + pxb + pl;
    const int ct0 = w * 6;
#pragma unroll 1
    for (int cti = 0; cti < 6; cti += 2) {
        int ct = ct0 + cti;
        f32x16 a2 = zero16(), a3 = zero16();
#pragma unroll
        for (int ms = 0; ms < 7; ++ms) {  // ms=7 has B==0, skipped
            U4H8 A0, A1, Bf;
            A0.u = mu4[(ct * 8 + ms) * 64 + l];
            A1.u = mu4[((ct + 1) * 8 + ms) * 64 + l];
            Bf.u = bfr[ms];
            a2 = __builtin_amdgcn_mfma_f32_32x32x16_f16(A0.h, Bf.h, a2, 0, 0, 0);
            a3 = __builtin_amdgcn_mfma_f32_32x32x16_f16(A1.h, Bf.h, a3, 0, 0, 0);
        }
#pragma unroll
        for (int r = 0; r < 16; ++r) {
            int cl = (r & 3) + 8 * (r >> 2) + 4 * h;
            __builtin_nontemporal_store(a2[r], &zo[(size_t)(ct * 32 + cl) * Nn]);
            __builtin_nontemporal_store(a3[r], &zo[(size_t)(ct * 32 + 32 + cl) * Nn]);
        }
    }
}

extern "C" void kernel_launch(void* const* d_in, const int* in_sizes, int n_in,
                              void* d_out, int out_size, void* d_ws, size_t ws_size,
                              hipStream_t stream) {
    const float* z = (const float*)d_in[0];
    const float* mem = (const float*)d_in[1];
    float* out = (float*)d_out;
    float* zhat = out;                          // 64*768*1024
    float* attn = out + (size_t)Bn * Cc * Nn;   // 64*1024*100
    _Float16* mhiF = (_Float16*)d_ws;           // 192 KB
    _Float16* mloF = mhiF + 48 * 4 * 64 * 8;    // 192 KB
    _Float16* muF = mloF + 48 * 4 * 64 * 8;     // 192 KB

    prep_kernel<<<128, 256, 0, stream>>>(mem, mhiF, mloF, muF);
    score_kernel<<<512, 256, 0, stream>>>(z, mhiF, mloF, attn);
    recon_kernel<<<2048, 256, 0, stream>>>(muF, attn, zhat);
}

// Round 12
// 112.183 us; speedup vs baseline: 1.4764x; 1.0439x over previous
//
#include <hip/hip_runtime.h>

#define EPSF 1e-8f

typedef __fp16   h2v   __attribute__((ext_vector_type(2)));
typedef _Float16 half8 __attribute__((ext_vector_type(8)));
typedef float    f32x16 __attribute__((ext_vector_type(16)));

constexpr int Bn = 64, Cc = 768, Nn = 1024, Mm = 100;

__device__ inline f32x16 zero16() {
    f32x16 z;
#pragma unroll
    for (int i = 0; i < 16; ++i) z[i] = 0.f;
    return z;
}

union U4H8 { uint4 u; half8 h; h2v p[4]; };

__device__ inline unsigned pkr(float a, float b) {
    union { h2v p; unsigned u; } cv;
    cv.p = __builtin_amdgcn_cvt_pkrtz(a, b);
    return cv.u;
}

// async global->LDS, 16 B per lane: LDS dest = wave-uniform base + lane*16.
__device__ inline void gload_lds16(const void* g, void* s) {
    __builtin_amdgcn_global_load_lds(
        (const __attribute__((address_space(1))) unsigned int*)g,
        (__attribute__((address_space(3))) unsigned int*)s, 16, 0, 0);
}

// Fragment-major prep (unchanged layouts).
// GEMM1 A (normalized mem, hi/lo f16):  idx = ((cs*4 + mt)*64 + hb*32 + ml)*8 + j
// GEMM2 A (raw mem, transposed):        idx = ((ct*8 + ms)*64 + hm*32 + cl)*8 + jm
__global__ __launch_bounds__(256) void prep_kernel(const float* __restrict__ mem,
                                                   _Float16* __restrict__ mhiF,
                                                   _Float16* __restrict__ mloF,
                                                   _Float16* __restrict__ muF) {
    int m = blockIdx.x, t = threadIdx.x;
    float inv = 0.f;
    if (m < Mm) {
        float ss = 0.f;
        for (int c = t; c < Cc; c += 256) { float v = mem[m * Cc + c]; ss += v * v; }
        __shared__ float red[256];
        red[t] = ss; __syncthreads();
        for (int s = 128; s > 0; s >>= 1) { if (t < s) red[t] += red[t + s]; __syncthreads(); }
        inv = 1.f / fmaxf(sqrtf(red[0]), 1e-12f);
    }
    for (int c = t; c < Cc; c += 256) {
        float v = (m < Mm) ? mem[m * Cc + c] : 0.f;
        float nv = v * inv;
        _Float16 hh = (_Float16)nv;
        _Float16 ll = (_Float16)(nv - (float)hh);
        int cs = c >> 4, hb = (c >> 3) & 1, j = c & 7, mt = m >> 5, ml = m & 31;
        size_t idx = ((size_t)(cs * 4 + mt) * 64 + hb * 32 + ml) * 8 + j;
        mhiF[idx] = hh;
        mloF[idx] = ll;
        int ct = c >> 5, cl = c & 31, ms = m >> 4, hm = (m >> 3) & 1, jm = m & 7;
        size_t idx2 = ((size_t)(ct * 8 + ms) * 64 + hm * 32 + cl) * 8 + jm;
        muF[idx2] = (_Float16)v;
    }
}

// Kernel A: 4 waves/block, one 32-px group per wave (2048 waves, 512 blocks =
// 2 blocks/CU). Fragments staged per-block into LDS 4 K-steps per round
// (ONE __syncthreads per round; issue staging+z-prefetch at round start so
// the barrier's vmcnt(0) drain lands ~1000cy after issue -> ~no stall).
__global__ __launch_bounds__(256) void score_kernel(
    const float* __restrict__ z, const _Float16* __restrict__ mhiF,
    const _Float16* __restrict__ mloF, float* __restrict__ attn_out) {
    __shared__ uint4 fbuf[2][4][2][256];  // [buf][step-in-round][hi/lo][mt*64+lane]  64 KB

    const int tid = threadIdx.x;
    const int w = tid >> 6;
    const int l = tid & 63;
    const int wid = (blockIdx.x << 2) | w;  // 0..2047
    const int b = wid >> 5;
    const int pxb = (wid & 31) * 32;
    const int pl = l & 31;
    const int h = l >> 5;
    const float* zr = z + (size_t)b * Cc * Nn + pxb + pl + (size_t)h * 8 * Nn;
    const uint4* mh4 = (const uint4*)mhiF;   // step s slice: +s*256
    const uint4* ml4 = (const uint4*)mloF;
    const uint4* gh = mh4 + w * 64 + l;      // wave w stages mt=w
    const uint4* gl = ml4 + w * 64 + l;

    f32x16 acc[4] = {zero16(), zero16(), zero16(), zero16()};
    float ss = 0.f;
    float zbufA[4][8], zbufB[4][8];

    // prologue: z for round 0 (steps 0..3) + staging round 0 -> fbuf[0]
#pragma unroll
    for (int i = 0; i < 4; ++i) {
#pragma unroll
        for (int j = 0; j < 8; ++j)
            zbufA[i][j] = __builtin_nontemporal_load(&zr[(size_t)(i * 16 + j) * Nn]);
        gload_lds16(gh + i * 256, &fbuf[0][i][0][w * 64]);
        gload_lds16(gl + i * 256, &fbuf[0][i][1][w * 64]);
    }
    __syncthreads();

    // one round: consume ZC + fbuf[FB]; prefetch next round into ZN + fbuf[FB^1]
    auto round_body = [&](int RR, float (&ZC)[4][8], float (&ZN)[4][8], int FB) {
        if (RR + 1 < 12) {
#pragma unroll
            for (int i = 0; i < 4; ++i) {  // stage next round's fragments (async)
                gload_lds16(gh + ((RR + 1) * 4 + i) * 256, &fbuf[FB ^ 1][i][0][w * 64]);
                gload_lds16(gl + ((RR + 1) * 4 + i) * 256, &fbuf[FB ^ 1][i][1][w * 64]);
            }
#pragma unroll
            for (int i = 0; i < 4; ++i)    // prefetch next round's z (nt)
#pragma unroll
                for (int j = 0; j < 8; ++j)
                    ZN[i][j] = __builtin_nontemporal_load(
                        &zr[(size_t)(((RR + 1) * 4 + i) * 16 + j) * Nn]);
        }
#pragma unroll
        for (int i = 0; i < 4; ++i) {      // compute 4 K-steps
            U4H8 zh, zl8;
#pragma unroll
            for (int t = 0; t < 4; ++t) {
                float u = ZC[i][2 * t], v = ZC[i][2 * t + 1];
                h2v p = __builtin_amdgcn_cvt_pkrtz(u, v);
                zh.p[t] = p;
                zl8.p[t] = __builtin_amdgcn_cvt_pkrtz(u - (float)p.x, v - (float)p.y);
                ss += u * u + v * v;
            }
            U4H8 ah, al;
#pragma unroll
            for (int mt = 0; mt < 4; ++mt) {
                ah.u = fbuf[FB][i][0][mt * 64 + l];
                al.u = fbuf[FB][i][1][mt * 64 + l];
                acc[mt] = __builtin_amdgcn_mfma_f32_32x32x16_f16(ah.h, zh.h, acc[mt], 0, 0, 0);
                acc[mt] = __builtin_amdgcn_mfma_f32_32x32x16_f16(al.h, zh.h, acc[mt], 0, 0, 0);
                acc[mt] = __builtin_amdgcn_mfma_f32_32x32x16_f16(ah.h, zl8.h, acc[mt], 0, 0, 0);
            }
        }
        __syncthreads();  // drains staging+z issued ~1000cy ago; swaps buffers
    };

#pragma unroll 1
    for (int rp = 0; rp < 6; ++rp) {
        round_body(2 * rp, zbufA, zbufB, 0);
        round_body(2 * rp + 1, zbufB, zbufA, 1);
    }

    // ---------------- in-register softmax + hard shrinkage ----------------
    ss += __shfl_xor(ss, 32);
    float invn = 1.f / fmaxf(sqrtf(ss), 1e-12f);

    float a_[64];
#pragma unroll
    for (int r = 0; r < 64; ++r) {
        int mt = r >> 4, rr = r & 15;
        float v = acc[mt][rr] * invn;
        if (r >= 52) v = -3.0e38f;
        else if (r >= 48) v = (h == 0) ? v : -3.0e38f;  // tile3: only m=96..99 valid
        a_[r] = v;
    }
    float mx = -3.0e38f;
#pragma unroll
    for (int r = 0; r < 52; ++r) mx = fmaxf(mx, a_[r]);
    mx = fmaxf(mx, __shfl_xor(mx, 32));

    float sum = 0.f;
#pragma unroll
    for (int r = 0; r < 52; ++r) { float e = expf(a_[r] - mx); a_[r] = e; sum += e; }
    sum += __shfl_xor(sum, 32);
    float itot = 1.f / sum;

    float asum = 0.f;
#pragma unroll
    for (int r = 0; r < 52; ++r) {
        float w_ = a_[r] * itot;
        float d = w_ - 0.01f;
        float aa = (d > 0.f) ? (d * w_) / (d + EPSF) : 0.f;
        a_[r] = aa; asum += aa;
    }
    asum += __shfl_xor(asum, 32);
    float ia = 1.f / (asum + EPSF);
#pragma unroll
    for (int r = 0; r < 52; ++r) a_[r] *= ia;

    // ---- store attn ----
    {
        size_t ob = (size_t)(wid * 32 + pl) * (size_t)Mm;
#pragma unroll
        for (int g = 0; g < 13; ++g) {
            int r0 = g * 4;
            int m0 = (r0 >> 4) * 32 + 8 * ((r0 >> 2) & 3) + 4 * h;
            if (g < 12 || h == 0) {
                float4 v = make_float4(a_[r0], a_[r0 + 1], a_[r0 + 2], a_[r0 + 3]);
                *(float4*)&attn_out[ob + m0] = v;
            }
        }
    }
}

// Kernel B: z_hat = attn @ memory (unchanged from round 11).
__global__ __launch_bounds__(256, 4) void recon_kernel(
    const _Float16* __restrict__ muF, const float* __restrict__ attn_out,
    float* __restrict__ zhat) {
    const int tid = threadIdx.x;
    const int w = tid >> 6;
    const int l = tid & 63;
    const int gb = blockIdx.x;
    const int b = gb >> 5;
    const int pxb = (gb & 31) * 32;
    const int pl = l & 31;
    const int h = l >> 5;

    const float* ap = attn_out + (size_t)(gb * 32 + pl) * (size_t)Mm;
    uint4 bfr[8];
#pragma unroll
    for (int ms = 0; ms < 6; ++ms) {
        float4 fa = *(const float4*)&ap[ms * 16 + h * 8];
        float4 fb = *(const float4*)&ap[ms * 16 + h * 8 + 4];
        bfr[ms] = make_uint4(pkr(fa.x, fa.y), pkr(fa.z, fa.w),
                             pkr(fb.x, fb.y), pkr(fb.z, fb.w));
    }
    {
        float4 fa = (h == 0) ? *(const float4*)&ap[96] : make_float4(0.f, 0.f, 0.f, 0.f);
        bfr[6] = make_uint4(pkr(fa.x, fa.y), pkr(fa.z, fa.w), 0u, 0u);
        bfr[7] = make_uint4(0u, 0u, 0u, 0u);
    }

    const uint4* mu4 = (const uint4*)muF;
    float* zo = zhat + (size_t)b * Cc * Nn + pxb + pl;
    const int ct0 = w * 6;
#pragma unroll 1
    for (int cti = 0; cti < 6; cti += 2) {
        int ct = ct0 + cti;
        f32x16 a2 = zero16(), a3 = zero16();
#pragma unroll
        for (int ms = 0; ms < 7; ++ms) {  // ms=7 has B==0, skipped
            U4H8 A0, A1, Bf;
            A0.u = mu4[(ct * 8 + ms) * 64 + l];
            A1.u = mu4[((ct + 1) * 8 + ms) * 64 + l];
            Bf.u = bfr[ms];
            a2 = __builtin_amdgcn_mfma_f32_32x32x16_f16(A0.h, Bf.h, a2, 0, 0, 0);
            a3 = __builtin_amdgcn_mfma_f32_32x32x16_f16(A1.h, Bf.h, a3, 0, 0, 0);
        }
#pragma unroll
        for (int r = 0; r < 16; ++r) {
            int cl = (r & 3) + 8 * (r >> 2) + 4 * h;
            __builtin_nontemporal_store(a2[r], &zo[(size_t)(ct * 32 + cl) * Nn]);
            __builtin_nontemporal_store(a3[r], &zo[(size_t)(ct * 32 + 32 + cl) * Nn]);
        }
    }
}

extern "C" void kernel_launch(void* const* d_in, const int* in_sizes, int n_in,
                              void* d_out, int out_size, void* d_ws, size_t ws_size,
                              hipStream_t stream) {
    const float* z = (const float*)d_in[0];
    const float* mem = (const float*)d_in[1];
    float* out = (float*)d_out;
    float* zhat = out;                          // 64*768*1024
    float* attn = out + (size_t)Bn * Cc * Nn;   // 64*1024*100
    _Float16* mhiF = (_Float16*)d_ws;           // 192 KB
    _Float16* mloF = mhiF + 48 * 4 * 64 * 8;    // 192 KB
    _Float16* muF = mloF + 48 * 4 * 64 * 8;     // 192 KB

    prep_kernel<<<128, 256, 0, stream>>>(mem, mhiF, mloF, muF);
    score_kernel<<<512, 256, 0, stream>>>(z, mhiF, mloF, attn);
    recon_kernel<<<2048, 256, 0, stream>>>(muF, attn, zhat);
}

// Round 13
// 112.173 us; speedup vs baseline: 1.4765x; 1.0001x over previous
//
#include <hip/hip_runtime.h>

#define EPSF 1e-8f

typedef __fp16   h2v   __attribute__((ext_vector_type(2)));
typedef _Float16 half8 __attribute__((ext_vector_type(8)));
typedef float    f32x16 __attribute__((ext_vector_type(16)));

constexpr int Bn = 64, Cc = 768, Nn = 1024, Mm = 100;

__device__ inline f32x16 zero16() {
    f32x16 z;
#pragma unroll
    for (int i = 0; i < 16; ++i) z[i] = 0.f;
    return z;
}

union U4H8 { uint4 u; half8 h; h2v p[4]; };

__device__ inline unsigned pkr(float a, float b) {
    union { h2v p; unsigned u; } cv;
    cv.p = __builtin_amdgcn_cvt_pkrtz(a, b);
    return cv.u;
}

// async global->LDS, 16 B per lane: LDS dest = wave-uniform base + lane*16.
__device__ inline void gload_lds16(const void* g, void* s) {
    __builtin_amdgcn_global_load_lds(
        (const __attribute__((address_space(1))) unsigned int*)g,
        (__attribute__((address_space(3))) unsigned int*)s, 16, 0, 0);
}

// Fragment-major prep (unchanged layouts).
// GEMM1 A (normalized mem, hi/lo f16):  idx = ((cs*4 + mt)*64 + hb*32 + ml)*8 + j
// GEMM2 A (raw mem, transposed):        idx = ((ct*8 + ms)*64 + hm*32 + cl)*8 + jm
__global__ __launch_bounds__(256) void prep_kernel(const float* __restrict__ mem,
                                                   _Float16* __restrict__ mhiF,
                                                   _Float16* __restrict__ mloF,
                                                   _Float16* __restrict__ muF) {
    int m = blockIdx.x, t = threadIdx.x;
    float inv = 0.f;
    if (m < Mm) {
        float ss = 0.f;
        for (int c = t; c < Cc; c += 256) { float v = mem[m * Cc + c]; ss += v * v; }
        __shared__ float red[256];
        red[t] = ss; __syncthreads();
        for (int s = 128; s > 0; s >>= 1) { if (t < s) red[t] += red[t + s]; __syncthreads(); }
        inv = 1.f / fmaxf(sqrtf(red[0]), 1e-12f);
    }
    for (int c = t; c < Cc; c += 256) {
        float v = (m < Mm) ? mem[m * Cc + c] : 0.f;
        float nv = v * inv;
        _Float16 hh = (_Float16)nv;
        _Float16 ll = (_Float16)(nv - (float)hh);
        int cs = c >> 4, hb = (c >> 3) & 1, j = c & 7, mt = m >> 5, ml = m & 31;
        size_t idx = ((size_t)(cs * 4 + mt) * 64 + hb * 32 + ml) * 8 + j;
        mhiF[idx] = hh;
        mloF[idx] = ll;
        int ct = c >> 5, cl = c & 31, ms = m >> 4, hm = (m >> 3) & 1, jm = m & 7;
        size_t idx2 = ((size_t)(ct * 8 + ms) * 64 + hm * 32 + cl) * 8 + jm;
        muF[idx2] = (_Float16)v;
    }
}

// Kernel A: round-12 structure + T4: raw s_barrier with COUNTED vmcnt(32)
// (waits only this wave's 8 staging ops; the 32 z prefetch loads stay in
// flight across the barrier instead of being drained by __syncthreads).
__global__ __launch_bounds__(256) void score_kernel(
    const float* __restrict__ z, const _Float16* __restrict__ mhiF,
    const _Float16* __restrict__ mloF, float* __restrict__ attn_out) {
    __shared__ uint4 fbuf[2][4][2][256];  // [buf][step-in-round][hi/lo][mt*64+lane]  64 KB

    const int tid = threadIdx.x;
    const int w = tid >> 6;
    const int l = tid & 63;
    const int wid = (blockIdx.x << 2) | w;  // 0..2047
    const int b = wid >> 5;
    const int pxb = (wid & 31) * 32;
    const int pl = l & 31;
    const int h = l >> 5;
    const float* zr = z + (size_t)b * Cc * Nn + pxb + pl + (size_t)h * 8 * Nn;
    const uint4* mh4 = (const uint4*)mhiF;   // step s slice: +s*256
    const uint4* ml4 = (const uint4*)mloF;
    const uint4* gh = mh4 + w * 64 + l;      // wave w stages mt=w
    const uint4* gl = ml4 + w * 64 + l;

    f32x16 acc[4] = {zero16(), zero16(), zero16(), zero16()};
    float ss = 0.f;
    float zbufA[4][8], zbufB[4][8];

    // prologue: stage round 0 (8 ops) then z round 0 (32 ops); wait ONLY the
    // staging (vmcnt(32) retires the 8 oldest), barrier. z stays in flight.
#pragma unroll
    for (int i = 0; i < 4; ++i) {
        gload_lds16(gh + i * 256, &fbuf[0][i][0][w * 64]);
        gload_lds16(gl + i * 256, &fbuf[0][i][1][w * 64]);
    }
#pragma unroll
    for (int i = 0; i < 4; ++i)
#pragma unroll
        for (int j = 0; j < 8; ++j)
            zbufA[i][j] = __builtin_nontemporal_load(&zr[(size_t)(i * 16 + j) * Nn]);
    __builtin_amdgcn_sched_barrier(0);
    asm volatile("s_waitcnt vmcnt(32)" ::: "memory");
    __builtin_amdgcn_sched_barrier(0);
    __builtin_amdgcn_s_barrier();
    __builtin_amdgcn_sched_barrier(0);

    // one round: consume ZC + fbuf[FB]; prefetch next round into ZN + fbuf[FB^1]
    auto round_body = [&](int RR, float (&ZC)[4][8], float (&ZN)[4][8], int FB) {
        const bool more = (RR + 1 < 12);
        if (more) {
#pragma unroll
            for (int i = 0; i < 4; ++i) {  // stage next round's fragments (async)
                gload_lds16(gh + ((RR + 1) * 4 + i) * 256, &fbuf[FB ^ 1][i][0][w * 64]);
                gload_lds16(gl + ((RR + 1) * 4 + i) * 256, &fbuf[FB ^ 1][i][1][w * 64]);
            }
#pragma unroll
            for (int i = 0; i < 4; ++i)    // prefetch next round's z (nt)
#pragma unroll
                for (int j = 0; j < 8; ++j)
                    ZN[i][j] = __builtin_nontemporal_load(
                        &zr[(size_t)(((RR + 1) * 4 + i) * 16 + j) * Nn]);
        }
#pragma unroll
        for (int i = 0; i < 4; ++i) {      // compute 4 K-steps
            U4H8 zh, zl8;
#pragma unroll
            for (int t = 0; t < 4; ++t) {
                float u = ZC[i][2 * t], v = ZC[i][2 * t + 1];
                h2v p = __builtin_amdgcn_cvt_pkrtz(u, v);
                zh.p[t] = p;
                zl8.p[t] = __builtin_amdgcn_cvt_pkrtz(u - (float)p.x, v - (float)p.y);
                ss += u * u + v * v;
            }
            U4H8 ah, al;
#pragma unroll
            for (int mt = 0; mt < 4; ++mt) {
                ah.u = fbuf[FB][i][0][mt * 64 + l];
                al.u = fbuf[FB][i][1][mt * 64 + l];
                acc[mt] = __builtin_amdgcn_mfma_f32_32x32x16_f16(ah.h, zh.h, acc[mt], 0, 0, 0);
                acc[mt] = __builtin_amdgcn_mfma_f32_32x32x16_f16(al.h, zh.h, acc[mt], 0, 0, 0);
                acc[mt] = __builtin_amdgcn_mfma_f32_32x32x16_f16(ah.h, zl8.h, acc[mt], 0, 0, 0);
            }
        }
        if (more) {
            // T4: wait only own staging (8 oldest of <=40 outstanding), then
            // raw barrier. Next round's 32 z loads remain in flight.
            __builtin_amdgcn_sched_barrier(0);
            asm volatile("s_waitcnt vmcnt(32)" ::: "memory");
            __builtin_amdgcn_sched_barrier(0);
            __builtin_amdgcn_s_barrier();
            __builtin_amdgcn_sched_barrier(0);
        }
    };

#pragma unroll 1
    for (int rp = 0; rp < 6; ++rp) {
        round_body(2 * rp, zbufA, zbufB, 0);
        round_body(2 * rp + 1, zbufB, zbufA, 1);
    }

    // ---------------- in-register softmax + hard shrinkage ----------------
    ss += __shfl_xor(ss, 32);
    float invn = 1.f / fmaxf(sqrtf(ss), 1e-12f);

    float a_[64];
#pragma unroll
    for (int r = 0; r < 64; ++r) {
        int mt = r >> 4, rr = r & 15;
        float v = acc[mt][rr] * invn;
        if (r >= 52) v = -3.0e38f;
        else if (r >= 48) v = (h == 0) ? v : -3.0e38f;  // tile3: only m=96..99 valid
        a_[r] = v;
    }
    float mx = -3.0e38f;
#pragma unroll
    for (int r = 0; r < 52; ++r) mx = fmaxf(mx, a_[r]);
    mx = fmaxf(mx, __shfl_xor(mx, 32));

    float sum = 0.f;
#pragma unroll
    for (int r = 0; r < 52; ++r) { float e = expf(a_[r] - mx); a_[r] = e; sum += e; }
    sum += __shfl_xor(sum, 32);
    float itot = 1.f / sum;

    float asum = 0.f;
#pragma unroll
    for (int r = 0; r < 52; ++r) {
        float w_ = a_[r] * itot;
        float d = w_ - 0.01f;
        float aa = (d > 0.f) ? (d * w_) / (d + EPSF) : 0.f;
        a_[r] = aa; asum += aa;
    }
    asum += __shfl_xor(asum, 32);
    float ia = 1.f / (asum + EPSF);
#pragma unroll
    for (int r = 0; r < 52; ++r) a_[r] *= ia;

    // ---- store attn ----
    {
        size_t ob = (size_t)(wid * 32 + pl) * (size_t)Mm;
#pragma unroll
        for (int g = 0; g < 13; ++g) {
            int r0 = g * 4;
            int m0 = (r0 >> 4) * 32 + 8 * ((r0 >> 2) & 3) + 4 * h;
            if (g < 12 || h == 0) {
                float4 v = make_float4(a_[r0], a_[r0 + 1], a_[r0 + 2], a_[r0 + 3]);
                *(float4*)&attn_out[ob + m0] = v;
            }
        }
    }
}

// Kernel B: z_hat = attn @ memory (unchanged from round 12).
__global__ __launch_bounds__(256, 4) void recon_kernel(
    const _Float16* __restrict__ muF, const float* __restrict__ attn_out,
    float* __restrict__ zhat) {
    const int tid = threadIdx.x;
    const int w = tid >> 6;
    const int l = tid & 63;
    const int gb = blockIdx.x;
    const int b = gb >> 5;
    const int pxb = (gb & 31) * 32;
    const int pl = l & 31;
    const int h = l >> 5;

    const float* ap = attn_out + (size_t)(gb * 32 + pl) * (size_t)Mm;
    uint4 bfr[8];
#pragma unroll
    for (int ms = 0; ms < 6; ++ms) {
        float4 fa = *(const float4*)&ap[ms * 16 + h * 8];
        float4 fb = *(const float4*)&ap[ms * 16 + h * 8 + 4];
        bfr[ms] = make_uint4(pkr(fa.x, fa.y), pkr(fa.z, fa.w),
                             pkr(fb.x, fb.y), pkr(fb.z, fb.w));
    }
    {
        float4 fa = (h == 0) ? *(const float4*)&ap[96] : make_float4(0.f, 0.f, 0.f, 0.f);
        bfr[6] = make_uint4(pkr(fa.x, fa.y), pkr(fa.z, fa.w), 0u, 0u);
        bfr[7] = make_uint4(0u, 0u, 0u, 0u);
    }

    const uint4* mu4 = (const uint4*)muF;
    float* zo = zhat + (size_t)b * Cc * Nn + pxb + pl;
    const int ct0 = w * 6;
#pragma unroll 1
    for (int cti = 0; cti < 6; cti += 2) {
        int ct = ct0 + cti;
        f32x16 a2 = zero16(), a3 = zero16();
#pragma unroll
        for (int ms = 0; ms < 7; ++ms) {  // ms=7 has B==0, skipped
            U4H8 A0, A1, Bf;
            A0.u = mu4[(ct * 8 + ms) * 64 + l];
            A1.u = mu4[((ct + 1) * 8 + ms) * 64 + l];
            Bf.u = bfr[ms];
            a2 = __builtin_amdgcn_mfma_f32_32x32x16_f16(A0.h, Bf.h, a2, 0, 0, 0);
            a3 = __builtin_amdgcn_mfma_f32_32x32x16_f16(A1.h, Bf.h, a3, 0, 0, 0);
        }
#pragma unroll
        for (int r = 0; r < 16; ++r) {
            int cl = (r & 3) + 8 * (r >> 2) + 4 * h;
            __builtin_nontemporal_store(a2[r], &zo[(size_t)(ct * 32 + cl) * Nn]);
            __builtin_nontemporal_store(a3[r], &zo[(size_t)(ct * 32 + 32 + cl) * Nn]);
        }
    }
}

extern "C" void kernel_launch(void* const* d_in, const int* in_sizes, int n_in,
                              void* d_out, int out_size, void* d_ws, size_t ws_size,
                              hipStream_t stream) {
    const float* z = (const float*)d_in[0];
    const float* mem = (const float*)d_in[1];
    float* out = (float*)d_out;
    float* zhat = out;                          // 64*768*1024
    float* attn = out + (size_t)Bn * Cc * Nn;   // 64*1024*100
    _Float16* mhiF = (_Float16*)d_ws;           // 192 KB
    _Float16* mloF = mhiF + 48 * 4 * 64 * 8;    // 192 KB
    _Float16* muF = mloF + 48 * 4 * 64 * 8;     // 192 KB

    prep_kernel<<<128, 256, 0, stream>>>(mem, mhiF, mloF, muF);
    score_kernel<<<512, 256, 0, stream>>>(z, mhiF, mloF, attn);
    recon_kernel<<<2048, 256, 0, stream>>>(muF, attn, zhat);
}